// Round 4
// baseline (3364.782 us; speedup 1.0000x reference)
//
#include <hip/hip_runtime.h>
#include <math.h>

#define SS 256      // sequence length S
#define BB 64       // batch B
#define EE 256      // embedding E
#define HD 256      // hidden per direction
#define G4 1024     // 4*HD
#define TT 16       // tags

__device__ __forceinline__ float sigm(float x) { return 1.0f / (1.0f + expf(-x)); }

// ---------------------------------------------------------------- init h (parity0, [dir][b][k]) + zero counters
__global__ __launch_bounds__(256) void k_init(const float* __restrict__ h0,
                                              float* __restrict__ hbuf,
                                              int* __restrict__ cnt) {
    int bid = blockIdx.x;
    if (bid < 128) {
        int i = bid * 256 + threadIdx.x;      // 32768 = 2*64*256
        hbuf[i] = h0[i];                      // parity0 = [dir][b][k] (same layout as h0)
    } else {
        for (int j = threadIdx.x; j < 2048; j += 256) cnt[j] = 0;
    }
}

// ---------------------------------------------------------------- input projection
// G_T[s][n(1024)][b(64)] = emb[token(s,b)] . W_ih[n] + (b_ih[n]+b_hh[n])
__global__ __launch_bounds__(256) void k_gemm_in(
    const int* __restrict__ token, const float* __restrict__ emb,
    const float* __restrict__ w_ih_f, const float* __restrict__ w_ih_b,
    const float* __restrict__ b_ih_f, const float* __restrict__ b_hh_f,
    const float* __restrict__ b_ih_b, const float* __restrict__ b_hh_b,
    float* __restrict__ GfT, float* __restrict__ GbT) {
    __shared__ float As[16][128];
    __shared__ float Bs[16][64];
    const int tid = threadIdx.x;
    const int m_base = blockIdx.x * 128;
    const int n_base = blockIdx.y * 64;
    const bool is_b = (n_base >= 1024);
    const float* W = is_b ? w_ih_b : w_ih_f;
    const int n_off = is_b ? (n_base - 1024) : n_base;

    const int a_mi = tid & 127;
    const int a_k4 = tid >> 7;
    const int m = m_base + a_mi;
    const int s_idx = m >> 6, b_idx = m & 63;
    const long emb_row = (long)token[b_idx * SS + s_idx] * EE;

    const int b_n = tid & 63;
    const int b_k4 = tid >> 6;
    const float* wrow = W + (long)(n_off + b_n) * EE;

    const int tx = tid & 15;   // m interleaved
    const int ty = tid >> 4;   // 4 n each
    float acc[8][4];
#pragma unroll
    for (int i = 0; i < 8; i++)
#pragma unroll
        for (int j = 0; j < 4; j++) acc[i][j] = 0.f;

    for (int kt = 0; kt < EE; kt += 16) {
        float4 av0 = *(const float4*)(emb + emb_row + kt + a_k4 * 8);
        float4 av1 = *(const float4*)(emb + emb_row + kt + a_k4 * 8 + 4);
        float4 bv  = *(const float4*)(wrow + kt + b_k4 * 4);
        __syncthreads();
        {
            int k0 = a_k4 * 8;
            As[k0 + 0][a_mi] = av0.x; As[k0 + 1][a_mi] = av0.y;
            As[k0 + 2][a_mi] = av0.z; As[k0 + 3][a_mi] = av0.w;
            As[k0 + 4][a_mi] = av1.x; As[k0 + 5][a_mi] = av1.y;
            As[k0 + 6][a_mi] = av1.z; As[k0 + 7][a_mi] = av1.w;
            int k1 = b_k4 * 4;
            Bs[k1 + 0][b_n] = bv.x; Bs[k1 + 1][b_n] = bv.y;
            Bs[k1 + 2][b_n] = bv.z; Bs[k1 + 3][b_n] = bv.w;
        }
        __syncthreads();
#pragma unroll
        for (int k = 0; k < 16; k++) {
            float am[8];
#pragma unroll
            for (int i = 0; i < 8; i++) am[i] = As[k][tx + 16 * i];
            float4 b0 = *(const float4*)&Bs[k][ty * 4];
            float bn[4] = {b0.x, b0.y, b0.z, b0.w};
#pragma unroll
            for (int i = 0; i < 8; i++)
#pragma unroll
                for (int j = 0; j < 4; j++)
                    acc[i][j] = fmaf(am[i], bn[j], acc[i][j]);
        }
    }
    const float* bi_p = is_b ? b_ih_b : b_ih_f;
    const float* bh_p = is_b ? b_hh_b : b_hh_f;
    float bb[4];
#pragma unroll
    for (int j = 0; j < 4; j++) {
        int n = n_off + ty * 4 + j;
        bb[j] = bi_p[n] + bh_p[n];
    }
    float* Gout = is_b ? GbT : GfT;
#pragma unroll
    for (int i = 0; i < 8; i++) {
        int mm = m_base + tx + 16 * i;
        int ss = mm >> 6, bbx = mm & 63;
#pragma unroll
        for (int j = 0; j < 4; j++) {
            long addr = ((long)ss * G4 + n_off + ty * 4 + j) * BB + bbx;
            Gout[addr] = acc[i][j] + bb[j];
        }
    }
}

// ---------------------------------------------------------------- persistent BiLSTM
// 256 wgs: dir = bid>>7, bg = (bid>>5)&3 (16 b), cg = bid&31 (8 cols).
// 256 thr: kh = tid>>7 (K half), col = (tid>>4)&7, b = tid&15.
// Sync: one counter per (dir,bg); 32 producers; relaxed add + relaxed polls;
// one agent release fence before add, one agent acquire fence after wait.
__global__ __launch_bounds__(256) void k_lstm(
    const float* __restrict__ GfT, const float* __restrict__ GbT,
    const float* __restrict__ whh_f, const float* __restrict__ whh_b,
    const float* __restrict__ c0,
    float* __restrict__ hbuf,    // [par][dir][b][k]
    float* __restrict__ hcat,    // [s][b][512]
    int* __restrict__ cnt) {
    __shared__ float Wt[256 * 36];   // [k][c*4+g], pitch 36
    __shared__ float Ht[16 * 260];   // [b][k], pitch 260
    __shared__ float Pd[128 * 4];
    const int tid = threadIdx.x;
    const int bid = blockIdx.x;
    const int dir = bid >> 7;
    const int bg  = (bid >> 5) & 3;
    const int cg  = bid & 31;
    const int colbase = cg * 8;
    const float* whh = dir ? whh_b : whh_f;
    const float* GT  = dir ? GbT : GfT;

    const int kh  = tid >> 7;
    const int col = (tid >> 4) & 7;
    const int b   = tid & 15;
    const int gb  = bg * 16 + b;
    const int gcol = colbase + col;

    // ---- preload W slice: Wt[k*36 + c*4 + g] = whh[g*256 + colbase + c][k]
    {
        int r = tid >> 3;              // 0..31 = c*4+g
        int c_ = r >> 2, g_ = r & 3;
        const float* src = whh + (long)(g_ * HD + colbase + c_) * HD;
        int kc = tid & 7;
#pragma unroll
        for (int j = 0; j < 8; ++j) {
            int k = kc * 32 + j * 4;
            float4 v = *(const float4*)(src + k);
            Wt[(k + 0) * 36 + r] = v.x;
            Wt[(k + 1) * 36 + r] = v.y;
            Wt[(k + 2) * 36 + r] = v.z;
            Wt[(k + 3) * 36 + r] = v.w;
        }
    }
    float cst = (kh == 0) ? c0[dir * (BB * HD) + gb * HD + gcol] : 0.f;

    int* myc = cnt + (dir * 4 + bg) * 256;   // counters 1 KB apart

    for (int t = 0; t < SS; ++t) {
        const int sidx = dir ? (SS - 1 - t) : t;
        const int par = t & 1;

        // G prefetch (independent of barrier-protected data)
        float g0 = 0, g1 = 0, g2 = 0, g3 = 0;
        if (kh == 0) {
            const float* Gs = GT + (long)sidx * (G4 * BB);
            g0 = Gs[(0 * HD + gcol) * BB + gb];
            g1 = Gs[(1 * HD + gcol) * BB + gb];
            g2 = Gs[(2 * HD + gcol) * BB + gb];
            g3 = Gs[(3 * HD + gcol) * BB + gb];
        }
        // stage Ht[b][k] from hbuf (b-major, float4 coalesced)
        {
            const float* hb = hbuf + (((long)par * 2 + dir) * BB + bg * 16) * HD;
            int sb = tid >> 4;        // 0..15
            int kc = tid & 15;
#pragma unroll
            for (int j = 0; j < 4; ++j) {
                int k = kc * 4 + j * 64;
                float4 v = *(const float4*)(hb + sb * HD + k);
                *(float4*)&Ht[sb * 260 + k] = v;
            }
        }
        __syncthreads();

        // matvec: 4 gates of (b, gcol) over K half [kh*128, kh*128+128)
        float a0 = 0, a1 = 0, a2 = 0, a3 = 0;
        {
            const float* hrow = &Ht[b * 260 + kh * 128];
            const float* wbase = &Wt[(kh * 128) * 36 + col * 4];
#pragma unroll 4
            for (int kk = 0; kk < 128; kk += 4) {
                float4 hv = *(const float4*)(hrow + kk);
                float4 w0 = *(const float4*)(wbase + (kk + 0) * 36);
                float4 w1 = *(const float4*)(wbase + (kk + 1) * 36);
                float4 w2 = *(const float4*)(wbase + (kk + 2) * 36);
                float4 w3 = *(const float4*)(wbase + (kk + 3) * 36);
                a0 = fmaf(hv.x, w0.x, a0); a1 = fmaf(hv.x, w0.y, a1);
                a2 = fmaf(hv.x, w0.z, a2); a3 = fmaf(hv.x, w0.w, a3);
                a0 = fmaf(hv.y, w1.x, a0); a1 = fmaf(hv.y, w1.y, a1);
                a2 = fmaf(hv.y, w1.z, a2); a3 = fmaf(hv.y, w1.w, a3);
                a0 = fmaf(hv.z, w2.x, a0); a1 = fmaf(hv.z, w2.y, a1);
                a2 = fmaf(hv.z, w2.z, a2); a3 = fmaf(hv.z, w2.w, a3);
                a0 = fmaf(hv.w, w3.x, a0); a1 = fmaf(hv.w, w3.y, a1);
                a2 = fmaf(hv.w, w3.z, a2); a3 = fmaf(hv.w, w3.w, a3);
            }
        }
        if (kh == 1) *(float4*)&Pd[(tid - 128) * 4] = make_float4(a0, a1, a2, a3);
        __syncthreads();

        if (kh == 0) {
            float4 p = *(const float4*)&Pd[tid * 4];
            float gi = g0 + a0 + p.x;
            float gf = g1 + a1 + p.y;
            float gg = g2 + a2 + p.z;
            float go = g3 + a3 + p.w;
            float cn = sigm(gf) * cst + sigm(gi) * tanhf(gg);
            float hn = sigm(go) * tanhf(cn);
            cst = cn;
            hcat[((long)sidx * BB + gb) * (2 * HD) + dir * HD + gcol] = hn;
            if (t < SS - 1)
                hbuf[((((long)(par ^ 1)) * 2 + dir) * BB + gb) * HD + gcol] = hn;
        }

        if (t < SS - 1) {
            __syncthreads();   // all waves' h stores issued before release
            if (tid == 0) {
                __builtin_amdgcn_fence(__ATOMIC_RELEASE, "agent");
                __hip_atomic_fetch_add(myc, 1, __ATOMIC_RELAXED, __HIP_MEMORY_SCOPE_AGENT);
                const int target = 32 * (t + 1);
                int budget = 1 << 16;
                while (__hip_atomic_load(myc, __ATOMIC_RELAXED, __HIP_MEMORY_SCOPE_AGENT) < target
                       && --budget) {}
                __builtin_amdgcn_fence(__ATOMIC_ACQUIRE, "agent");
            }
            __syncthreads();
        }
    }
}

// ---------------------------------------------------------------- tag projection
__global__ __launch_bounds__(256) void k_feats(const float* __restrict__ hcat,
                                               const float* __restrict__ W_tag,
                                               const float* __restrict__ b_tag,
                                               float* __restrict__ feats) {
    __shared__ float WT[512 * 16];
    __shared__ float bt[16];
    const int tid = threadIdx.x;
    {
        int n = tid >> 4, kc = tid & 15;
#pragma unroll
        for (int j = 0; j < 8; ++j) {
            int k = kc * 32 + j * 4;
            float4 v = *(const float4*)(W_tag + n * 512 + k);
            int nn = (n + kc) & 15;                    // swizzle by k>>5
            WT[(k + 0) * 16 + nn] = v.x;
            WT[(k + 1) * 16 + nn] = v.y;
            WT[(k + 2) * 16 + nn] = v.z;
            WT[(k + 3) * 16 + nn] = v.w;
        }
    }
    if (tid < 16) bt[tid] = b_tag[tid];
    __syncthreads();
    const int lane = tid & 63;
    const int wv = tid >> 6;
    const int n = lane & 15;
    const long m = (long)blockIdx.x * 16 + wv * 4 + (lane >> 4);
    const float* hr = hcat + m * 512;
    float acc = 0.f;
#pragma unroll 8
    for (int k = 0; k < 512; k += 4) {
        float4 h = *(const float4*)(hr + k);
        int nn = (n + (k >> 5)) & 15;
        float w0 = WT[(k + 0) * 16 + nn];
        float w1 = WT[(k + 1) * 16 + nn];
        float w2 = WT[(k + 2) * 16 + nn];
        float w3 = WT[(k + 3) * 16 + nn];
        acc = fmaf(h.x, w0, fmaf(h.y, w1, fmaf(h.z, w2, fmaf(h.w, w3, acc))));
    }
    feats[m * TT + n] = acc + bt[n];
}

// ---------------------------------------------------------------- Viterbi + backtrack
__global__ __launch_bounds__(64) void k_viterbi(const float* __restrict__ feats,
                                                const float* __restrict__ trans,
                                                int* __restrict__ out) {
    __shared__ float tr[16][17];
    __shared__ float fv[2][4][16];
    __shared__ unsigned char bp[4][256][16];
    const int lane = threadIdx.x;
    const int bi = lane >> 4, nx = lane & 15;
    const int b = blockIdx.x * 4 + bi;

    for (int i = lane; i < 256; i += 64) tr[i >> 4][i & 15] = trans[i];
    fv[0][bi][nx] = (nx == 14) ? 0.f : -10000.f;   // START = 14
    __syncthreads();

    int cur = 0;
    for (int s = 0; s < SS; s++) {
        float fe = feats[((long)s * BB + b) * TT + nx];
        float best = -3.4e38f;
        int bestp = 0;
#pragma unroll
        for (int p = 0; p < 16; p++) {
            float sc = (fv[cur][bi][p] + tr[nx][p]) + fe;  // ref op order
            if (sc > best) { best = sc; bestp = p; }       // first-max wins
        }
        fv[cur ^ 1][bi][nx] = best;
        bp[bi][s][nx] = (unsigned char)bestp;
        __syncthreads();
        cur ^= 1;
    }
    float bv = fv[cur][bi][nx] + tr[15][nx];       // STOP = 15
    int bidx = nx;
#pragma unroll
    for (int off = 1; off < 16; off <<= 1) {
        float ov = __shfl_xor(bv, off, 64);
        int oi = __shfl_xor(bidx, off, 64);
        if (ov > bv || (ov == bv && oi < bidx)) { bv = ov; bidx = oi; }
    }
    if (nx == 0) {
        int tag = bidx;
        for (int s = SS - 1; s > 0; --s) {
            out[b * SS + s] = tag;
            tag = bp[bi][s][tag];
        }
        out[b * SS] = tag;
    }
}

// ---------------------------------------------------------------- launcher
extern "C" void kernel_launch(void* const* d_in, const int* in_sizes, int n_in,
                              void* d_out, int out_size, void* d_ws, size_t ws_size,
                              hipStream_t stream) {
    const int*   token  = (const int*)  d_in[0];
    const float* emb    = (const float*)d_in[1];
    const float* w_ih_f = (const float*)d_in[2];
    const float* w_hh_f = (const float*)d_in[3];
    const float* b_ih_f = (const float*)d_in[4];
    const float* b_hh_f = (const float*)d_in[5];
    const float* w_ih_b = (const float*)d_in[6];
    const float* w_hh_b = (const float*)d_in[7];
    const float* b_ih_b = (const float*)d_in[8];
    const float* b_hh_b = (const float*)d_in[9];
    const float* W_tag  = (const float*)d_in[10];
    const float* b_tag  = (const float*)d_in[11];
    const float* trans  = (const float*)d_in[12];
    const float* h0     = (const float*)d_in[13];
    const float* c0     = (const float*)d_in[14];
    int* out = (int*)d_out;

    char* ws = (char*)d_ws;
    float* GfT   = (float*)(ws);                                     // 64 MiB
    float* GbT   = (float*)(ws + ((size_t)64 << 20));                // 64 MiB
    float* hcat  = (float*)(ws + ((size_t)128 << 20));               // 32 MiB
    float* feats = (float*)(ws + ((size_t)160 << 20));               // 1 MiB
    float* hbuf  = (float*)(ws + ((size_t)161 << 20));               // 256 KiB
    int*   cnt   = (int*)  (ws + ((size_t)161 << 20) + (512 << 10)); // 8 KiB

    k_init<<<dim3(129), dim3(256), 0, stream>>>(h0, hbuf, cnt);
    k_gemm_in<<<dim3(128, 32), dim3(256), 0, stream>>>(
        token, emb, w_ih_f, w_ih_b, b_ih_f, b_hh_f, b_ih_b, b_hh_b, GfT, GbT);
    k_lstm<<<dim3(256), dim3(256), 0, stream>>>(
        GfT, GbT, w_hh_f, w_hh_b, c0, hbuf, hcat, cnt);
    k_feats<<<dim3(1024), dim3(256), 0, stream>>>(hcat, W_tag, b_tag, feats);
    k_viterbi<<<dim3(16), dim3(64), 0, stream>>>(feats, trans, out);
}

// Round 6
// 1635.807 us; speedup vs baseline: 2.0570x; 2.0570x over previous
//
#include <hip/hip_runtime.h>
#include <math.h>

#define SS 256      // sequence length S
#define BB 64       // batch B
#define EE 256      // embedding E
#define HD 256      // hidden per direction
#define G4 1024     // 4*HD
#define TT 16       // tags

__device__ __forceinline__ float sigm(float x) { return 1.0f / (1.0f + expf(-x)); }

// ---- device-coherent (Infinity-Cache) accessors: bypass L1/L2, no fences needed
__device__ __forceinline__ void ld4x_sc(const float* p0, const float* p1,
                                        const float* p2, const float* p3,
                                        float4& r0, float4& r1,
                                        float4& r2, float4& r3) {
    asm volatile(
        "global_load_dwordx4 %0, %4, off sc0 sc1\n\t"
        "global_load_dwordx4 %1, %5, off sc0 sc1\n\t"
        "global_load_dwordx4 %2, %6, off sc0 sc1\n\t"
        "global_load_dwordx4 %3, %7, off sc0 sc1\n\t"
        "s_waitcnt vmcnt(0)"
        : "=&v"(r0), "=&v"(r1), "=&v"(r2), "=&v"(r3)
        : "v"(p0), "v"(p1), "v"(p2), "v"(p3)
        : "memory");
}
__device__ __forceinline__ void st_sc(float* p, float v) {
    asm volatile(
        "global_store_dword %0, %1, off sc0 sc1\n\t"
        "s_waitcnt vmcnt(0)"
        :: "v"(p), "v"(v)
        : "memory");
}

// ---------------------------------------------------------------- init h (parity0, [dir][b][k]) + zero counters
__global__ __launch_bounds__(256) void k_init(const float* __restrict__ h0,
                                              float* __restrict__ hbuf,
                                              int* __restrict__ cnt) {
    int bid = blockIdx.x;
    if (bid < 128) {
        int i = bid * 256 + threadIdx.x;      // 32768 = 2*64*256
        hbuf[i] = h0[i];                      // parity0 = [dir][b][k]
    } else {
        for (int j = threadIdx.x; j < 2048; j += 256) cnt[j] = 0;
    }
}

// ---------------------------------------------------------------- input projection
// G_T[s][n(1024)][b(64)] = emb[token(s,b)] . W_ih[n] + (b_ih[n]+b_hh[n])
__global__ __launch_bounds__(256) void k_gemm_in(
    const int* __restrict__ token, const float* __restrict__ emb,
    const float* __restrict__ w_ih_f, const float* __restrict__ w_ih_b,
    const float* __restrict__ b_ih_f, const float* __restrict__ b_hh_f,
    const float* __restrict__ b_ih_b, const float* __restrict__ b_hh_b,
    float* __restrict__ GfT, float* __restrict__ GbT) {
    __shared__ float As[16][128];
    __shared__ float Bs[16][64];
    const int tid = threadIdx.x;
    const int m_base = blockIdx.x * 128;
    const int n_base = blockIdx.y * 64;
    const bool is_b = (n_base >= 1024);
    const float* W = is_b ? w_ih_b : w_ih_f;
    const int n_off = is_b ? (n_base - 1024) : n_base;

    const int a_mi = tid & 127;
    const int a_k4 = tid >> 7;
    const int m = m_base + a_mi;
    const int s_idx = m >> 6, b_idx = m & 63;
    const long emb_row = (long)token[b_idx * SS + s_idx] * EE;

    const int b_n = tid & 63;
    const int b_k4 = tid >> 6;
    const float* wrow = W + (long)(n_off + b_n) * EE;

    const int tx = tid & 15;   // m interleaved
    const int ty = tid >> 4;   // 4 n each
    float acc[8][4];
#pragma unroll
    for (int i = 0; i < 8; i++)
#pragma unroll
        for (int j = 0; j < 4; j++) acc[i][j] = 0.f;

    for (int kt = 0; kt < EE; kt += 16) {
        float4 av0 = *(const float4*)(emb + emb_row + kt + a_k4 * 8);
        float4 av1 = *(const float4*)(emb + emb_row + kt + a_k4 * 8 + 4);
        float4 bv  = *(const float4*)(wrow + kt + b_k4 * 4);
        __syncthreads();
        {
            int k0 = a_k4 * 8;
            As[k0 + 0][a_mi] = av0.x; As[k0 + 1][a_mi] = av0.y;
            As[k0 + 2][a_mi] = av0.z; As[k0 + 3][a_mi] = av0.w;
            As[k0 + 4][a_mi] = av1.x; As[k0 + 5][a_mi] = av1.y;
            As[k0 + 6][a_mi] = av1.z; As[k0 + 7][a_mi] = av1.w;
            int k1 = b_k4 * 4;
            Bs[k1 + 0][b_n] = bv.x; Bs[k1 + 1][b_n] = bv.y;
            Bs[k1 + 2][b_n] = bv.z; Bs[k1 + 3][b_n] = bv.w;
        }
        __syncthreads();
#pragma unroll
        for (int k = 0; k < 16; k++) {
            float am[8];
#pragma unroll
            for (int i = 0; i < 8; i++) am[i] = As[k][tx + 16 * i];
            float4 b0 = *(const float4*)&Bs[k][ty * 4];
            float bn[4] = {b0.x, b0.y, b0.z, b0.w};
#pragma unroll
            for (int i = 0; i < 8; i++)
#pragma unroll
                for (int j = 0; j < 4; j++)
                    acc[i][j] = fmaf(am[i], bn[j], acc[i][j]);
        }
    }
    const float* bi_p = is_b ? b_ih_b : b_ih_f;
    const float* bh_p = is_b ? b_hh_b : b_hh_f;
    float bb[4];
#pragma unroll
    for (int j = 0; j < 4; j++) {
        int n = n_off + ty * 4 + j;
        bb[j] = bi_p[n] + bh_p[n];
    }
    float* Gout = is_b ? GbT : GfT;
#pragma unroll
    for (int i = 0; i < 8; i++) {
        int mm = m_base + tx + 16 * i;
        int ss = mm >> 6, bbx = mm & 63;
#pragma unroll
        for (int j = 0; j < 4; j++) {
            long addr = ((long)ss * G4 + n_off + ty * 4 + j) * BB + bbx;
            Gout[addr] = acc[i][j] + bb[j];
        }
    }
}

// ---------------------------------------------------------------- persistent BiLSTM
// 256 wgs: dir = bid>>7, bg = (bid>>5)&3 (16 b), cg = bid&31 (8 cols).
// 256 thr: kh = tid>>7 (K half), col = (tid>>4)&7, b = tid&15.
// Sync: one counter per (dir,bg); h exchange via IC-coherent sc0/sc1 accesses;
// NO cache-maintenance fences anywhere.
__global__ __launch_bounds__(256) void k_lstm(
    const float* __restrict__ GfT, const float* __restrict__ GbT,
    const float* __restrict__ whh_f, const float* __restrict__ whh_b,
    const float* __restrict__ c0,
    float* __restrict__ hbuf,    // [par][dir][b][k]
    float* __restrict__ hcat,    // [s][b][512]
    int* __restrict__ cnt) {
    __shared__ float Wt[256 * 36];   // [k][c*4+g], pitch 36
    __shared__ float Ht[16 * 260];   // [b][k], pitch 260
    __shared__ float Pd[128 * 4];
    const int tid = threadIdx.x;
    const int bid = blockIdx.x;
    const int dir = bid >> 7;
    const int bg  = (bid >> 5) & 3;
    const int cg  = bid & 31;
    const int colbase = cg * 8;
    const float* whh = dir ? whh_b : whh_f;
    const float* GT  = dir ? GbT : GfT;

    const int kh  = tid >> 7;
    const int col = (tid >> 4) & 7;
    const int b   = tid & 15;
    const int gb  = bg * 16 + b;
    const int gcol = colbase + col;

    // ---- preload W slice: Wt[k*36 + c*4 + g] = whh[g*256 + colbase + c][k]
    {
        int r = tid >> 3;              // 0..31 = c*4+g
        int c_ = r >> 2, g_ = r & 3;
        const float* src = whh + (long)(g_ * HD + colbase + c_) * HD;
        int kc = tid & 7;
#pragma unroll
        for (int j = 0; j < 8; ++j) {
            int k = kc * 32 + j * 4;
            float4 v = *(const float4*)(src + k);
            Wt[(k + 0) * 36 + r] = v.x;
            Wt[(k + 1) * 36 + r] = v.y;
            Wt[(k + 2) * 36 + r] = v.z;
            Wt[(k + 3) * 36 + r] = v.w;
        }
    }
    float cst = (kh == 0) ? c0[dir * (BB * HD) + gb * HD + gcol] : 0.f;

    int* myc = cnt + (dir * 4 + bg) * 256;   // counters 1 KB apart

    for (int t = 0; t < SS; ++t) {
        const int sidx = dir ? (SS - 1 - t) : t;
        const int par = t & 1;

        // stage Ht[b][k] from hbuf via coherent loads (b-major, float4 coalesced)
        {
            const float* hb = hbuf + (((long)par * 2 + dir) * BB + bg * 16) * HD;
            int sb = tid >> 4;        // 0..15
            int kc = tid & 15;
            const float* base = hb + sb * HD + kc * 4;
            float4 v0, v1, v2, v3;
            ld4x_sc(base, base + 64, base + 128, base + 192, v0, v1, v2, v3);
            *(float4*)&Ht[sb * 260 + kc * 4 +   0] = v0;
            *(float4*)&Ht[sb * 260 + kc * 4 +  64] = v1;
            *(float4*)&Ht[sb * 260 + kc * 4 + 128] = v2;
            *(float4*)&Ht[sb * 260 + kc * 4 + 192] = v3;
        }
        // G prefetch (plain cached loads; latency hides under matvec)
        float g0 = 0, g1 = 0, g2 = 0, g3 = 0;
        if (kh == 0) {
            const float* Gs = GT + (long)sidx * (G4 * BB);
            g0 = Gs[(0 * HD + gcol) * BB + gb];
            g1 = Gs[(1 * HD + gcol) * BB + gb];
            g2 = Gs[(2 * HD + gcol) * BB + gb];
            g3 = Gs[(3 * HD + gcol) * BB + gb];
        }
        __syncthreads();

        // matvec: 4 gates of (b, gcol) over K half [kh*128, kh*128+128)
        float a0 = 0, a1 = 0, a2 = 0, a3 = 0;
        {
            const float* hrow = &Ht[b * 260 + kh * 128];
            const float* wbase = &Wt[(kh * 128) * 36 + col * 4];
#pragma unroll 4
            for (int kk = 0; kk < 128; kk += 4) {
                float4 hv = *(const float4*)(hrow + kk);
                float4 w0 = *(const float4*)(wbase + (kk + 0) * 36);
                float4 w1 = *(const float4*)(wbase + (kk + 1) * 36);
                float4 w2 = *(const float4*)(wbase + (kk + 2) * 36);
                float4 w3 = *(const float4*)(wbase + (kk + 3) * 36);
                a0 = fmaf(hv.x, w0.x, a0); a1 = fmaf(hv.x, w0.y, a1);
                a2 = fmaf(hv.x, w0.z, a2); a3 = fmaf(hv.x, w0.w, a3);
                a0 = fmaf(hv.y, w1.x, a0); a1 = fmaf(hv.y, w1.y, a1);
                a2 = fmaf(hv.y, w1.z, a2); a3 = fmaf(hv.y, w1.w, a3);
                a0 = fmaf(hv.z, w2.x, a0); a1 = fmaf(hv.z, w2.y, a1);
                a2 = fmaf(hv.z, w2.z, a2); a3 = fmaf(hv.z, w2.w, a3);
                a0 = fmaf(hv.w, w3.x, a0); a1 = fmaf(hv.w, w3.y, a1);
                a2 = fmaf(hv.w, w3.z, a2); a3 = fmaf(hv.w, w3.w, a3);
            }
        }
        if (kh == 1) *(float4*)&Pd[(tid - 128) * 4] = make_float4(a0, a1, a2, a3);
        __syncthreads();

        if (kh == 0) {
            float4 p = *(const float4*)&Pd[tid * 4];
            float gi = g0 + a0 + p.x;
            float gf = g1 + a1 + p.y;
            float gg = g2 + a2 + p.z;
            float go = g3 + a3 + p.w;
            float cn = sigm(gf) * cst + sigm(gi) * tanhf(gg);
            float hn = sigm(go) * tanhf(cn);
            cst = cn;
            hcat[((long)sidx * BB + gb) * (2 * HD) + dir * HD + gcol] = hn;
            if (t < SS - 1)
                st_sc(&hbuf[((((long)(par ^ 1)) * 2 + dir) * BB + gb) * HD + gcol], hn);
        }

        if (t < SS - 1) {
            __syncthreads();   // all wg h-stores complete (waitcnt inside st_sc)
            if (tid == 0) {
                __hip_atomic_fetch_add(myc, 1, __ATOMIC_RELAXED, __HIP_MEMORY_SCOPE_AGENT);
                const int target = 32 * (t + 1);
                int budget = 1 << 20;   // deadlock escape only; never expected
                while (__hip_atomic_load(myc, __ATOMIC_RELAXED, __HIP_MEMORY_SCOPE_AGENT) < target
                       && --budget) {}
            }
            __syncthreads();
        }
    }
}

// ---------------------------------------------------------------- tag projection
__global__ __launch_bounds__(256) void k_feats(const float* __restrict__ hcat,
                                               const float* __restrict__ W_tag,
                                               const float* __restrict__ b_tag,
                                               float* __restrict__ feats) {
    __shared__ float WT[512 * 16];
    __shared__ float bt[16];
    const int tid = threadIdx.x;
    {
        int n = tid >> 4, kc = tid & 15;
#pragma unroll
        for (int j = 0; j < 8; ++j) {
            int k = kc * 32 + j * 4;
            float4 v = *(const float4*)(W_tag + n * 512 + k);
            int nn = (n + kc) & 15;                    // swizzle by k>>5
            WT[(k + 0) * 16 + nn] = v.x;
            WT[(k + 1) * 16 + nn] = v.y;
            WT[(k + 2) * 16 + nn] = v.z;
            WT[(k + 3) * 16 + nn] = v.w;
        }
    }
    if (tid < 16) bt[tid] = b_tag[tid];
    __syncthreads();
    const int lane = tid & 63;
    const int wv = tid >> 6;
    const int n = lane & 15;
    const long m = (long)blockIdx.x * 16 + wv * 4 + (lane >> 4);
    const float* hr = hcat + m * 512;
    float acc = 0.f;
#pragma unroll 8
    for (int k = 0; k < 512; k += 4) {
        float4 h = *(const float4*)(hr + k);
        int nn = (n + (k >> 5)) & 15;
        float w0 = WT[(k + 0) * 16 + nn];
        float w1 = WT[(k + 1) * 16 + nn];
        float w2 = WT[(k + 2) * 16 + nn];
        float w3 = WT[(k + 3) * 16 + nn];
        acc = fmaf(h.x, w0, fmaf(h.y, w1, fmaf(h.z, w2, fmaf(h.w, w3, acc))));
    }
    feats[m * TT + n] = acc + bt[n];
}

// ---------------------------------------------------------------- Viterbi + backtrack
__global__ __launch_bounds__(64) void k_viterbi(const float* __restrict__ feats,
                                                const float* __restrict__ trans,
                                                int* __restrict__ out) {
    __shared__ float tr[16][17];
    __shared__ float fv[2][4][16];
    __shared__ unsigned char bp[4][256][16];
    const int lane = threadIdx.x;
    const int bi = lane >> 4, nx = lane & 15;
    const int b = blockIdx.x * 4 + bi;

    for (int i = lane; i < 256; i += 64) tr[i >> 4][i & 15] = trans[i];
    fv[0][bi][nx] = (nx == 14) ? 0.f : -10000.f;   // START = 14
    __syncthreads();

    int cur = 0;
    for (int s = 0; s < SS; s++) {
        float fe = feats[((long)s * BB + b) * TT + nx];
        float best = -3.4e38f;
        int bestp = 0;
#pragma unroll
        for (int p = 0; p < 16; p++) {
            float sc = (fv[cur][bi][p] + tr[nx][p]) + fe;  // ref op order
            if (sc > best) { best = sc; bestp = p; }       // first-max wins
        }
        fv[cur ^ 1][bi][nx] = best;
        bp[bi][s][nx] = (unsigned char)bestp;
        __syncthreads();
        cur ^= 1;
    }
    float bv = fv[cur][bi][nx] + tr[15][nx];       // STOP = 15
    int bidx = nx;
#pragma unroll
    for (int off = 1; off < 16; off <<= 1) {
        float ov = __shfl_xor(bv, off, 64);
        int oi = __shfl_xor(bidx, off, 64);
        if (ov > bv || (ov == bv && oi < bidx)) { bv = ov; bidx = oi; }
    }
    if (nx == 0) {
        int tag = bidx;
        for (int s = SS - 1; s > 0; --s) {
            out[b * SS + s] = tag;
            tag = bp[bi][s][tag];
        }
        out[b * SS] = tag;
    }
}

// ---------------------------------------------------------------- launcher
extern "C" void kernel_launch(void* const* d_in, const int* in_sizes, int n_in,
                              void* d_out, int out_size, void* d_ws, size_t ws_size,
                              hipStream_t stream) {
    const int*   token  = (const int*)  d_in[0];
    const float* emb    = (const float*)d_in[1];
    const float* w_ih_f = (const float*)d_in[2];
    const float* w_hh_f = (const float*)d_in[3];
    const float* b_ih_f = (const float*)d_in[4];
    const float* b_hh_f = (const float*)d_in[5];
    const float* w_ih_b = (const float*)d_in[6];
    const float* w_hh_b = (const float*)d_in[7];
    const float* b_ih_b = (const float*)d_in[8];
    const float* b_hh_b = (const float*)d_in[9];
    const float* W_tag  = (const float*)d_in[10];
    const float* b_tag  = (const float*)d_in[11];
    const float* trans  = (const float*)d_in[12];
    const float* h0     = (const float*)d_in[13];
    const float* c0     = (const float*)d_in[14];
    int* out = (int*)d_out;

    char* ws = (char*)d_ws;
    float* GfT   = (float*)(ws);                                     // 64 MiB
    float* GbT   = (float*)(ws + ((size_t)64 << 20));                // 64 MiB
    float* hcat  = (float*)(ws + ((size_t)128 << 20));               // 32 MiB
    float* feats = (float*)(ws + ((size_t)160 << 20));               // 1 MiB
    float* hbuf  = (float*)(ws + ((size_t)161 << 20));               // 256 KiB
    int*   cnt   = (int*)  (ws + ((size_t)161 << 20) + (512 << 10)); // 8 KiB

    k_init<<<dim3(129), dim3(256), 0, stream>>>(h0, hbuf, cnt);
    k_gemm_in<<<dim3(128, 32), dim3(256), 0, stream>>>(
        token, emb, w_ih_f, w_ih_b, b_ih_f, b_hh_f, b_ih_b, b_hh_b, GfT, GbT);
    k_lstm<<<dim3(256), dim3(256), 0, stream>>>(
        GfT, GbT, w_hh_f, w_hh_b, c0, hbuf, hcat, cnt);
    k_feats<<<dim3(1024), dim3(256), 0, stream>>>(hcat, W_tag, b_tag, feats);
    k_viterbi<<<dim3(16), dim3(64), 0, stream>>>(feats, trans, out);
}

// Round 8
// 1459.138 us; speedup vs baseline: 2.3060x; 1.1211x over previous
//
#include <hip/hip_runtime.h>
#include <math.h>

#define SS 256      // sequence length S
#define BB 64       // batch B
#define EE 256      // embedding E
#define HD 256      // hidden per direction
#define G4 1024     // 4*HD
#define TT 16       // tags
#define HTP 20      // Ht pitch (floats)
#define PDP 36      // Pd row pitch
#define PDS 576     // Pd kq slab (16*36)

__device__ __forceinline__ float sigm(float x) { return 1.0f / (1.0f + expf(-x)); }

// ---- device-coherent (Infinity-Cache) accessors: bypass L1/L2, no fences needed
__device__ __forceinline__ void ld4x_sc(const float* p0, const float* p1,
                                        const float* p2, const float* p3,
                                        float4& r0, float4& r1,
                                        float4& r2, float4& r3) {
    asm volatile(
        "global_load_dwordx4 %0, %4, off sc0 sc1\n\t"
        "global_load_dwordx4 %1, %5, off sc0 sc1\n\t"
        "global_load_dwordx4 %2, %6, off sc0 sc1\n\t"
        "global_load_dwordx4 %3, %7, off sc0 sc1\n\t"
        "s_waitcnt vmcnt(0)"
        : "=&v"(r0), "=&v"(r1), "=&v"(r2), "=&v"(r3)
        : "v"(p0), "v"(p1), "v"(p2), "v"(p3)
        : "memory");
}
__device__ __forceinline__ void st_sc(float* p, float v) {
    asm volatile(
        "global_store_dword %0, %1, off sc0 sc1\n\t"
        "s_waitcnt vmcnt(0)"
        :: "v"(p), "v"(v)
        : "memory");
}
__device__ __forceinline__ int ld_sc_int(const int* p) {
    int v;
    asm volatile(
        "global_load_dword %0, %1, off sc0 sc1\n\t"
        "s_waitcnt vmcnt(0)"
        : "=v"(v) : "v"(p) : "memory");
    return v;
}

// ---------------------------------------------------------------- init h (parity0) + zero counters
// hbufT2 layout: [par][dir][bg(4)][k(256)][b(16)]
__global__ __launch_bounds__(256) void k_init(const float* __restrict__ h0,
                                              float* __restrict__ hbufT2,
                                              int* __restrict__ cnt) {
    int bid = blockIdx.x;
    if (bid < 128) {
        int i = bid * 256 + threadIdx.x;      // 32768 = 2*64*256 ; h0 = [dir][b][k]
        int dir = i >> 14, b = (i >> 8) & 63, k = i & 255;
        hbufT2[((dir * 4) + (b >> 4)) * 4096 + k * 16 + (b & 15)] = h0[i];
    } else {
        for (int j = threadIdx.x; j < 2048; j += 256) cnt[j] = 0;
    }
}

// ---------------------------------------------------------------- input projection
// G_T[s][n(1024)][b(64)] = emb[token(s,b)] . W_ih[n] + (b_ih[n]+b_hh[n])
__global__ __launch_bounds__(256) void k_gemm_in(
    const int* __restrict__ token, const float* __restrict__ emb,
    const float* __restrict__ w_ih_f, const float* __restrict__ w_ih_b,
    const float* __restrict__ b_ih_f, const float* __restrict__ b_hh_f,
    const float* __restrict__ b_ih_b, const float* __restrict__ b_hh_b,
    float* __restrict__ GfT, float* __restrict__ GbT) {
    __shared__ float As[16][128];
    __shared__ float Bs[16][64];
    const int tid = threadIdx.x;
    const int m_base = blockIdx.x * 128;
    const int n_base = blockIdx.y * 64;
    const bool is_b = (n_base >= 1024);
    const float* W = is_b ? w_ih_b : w_ih_f;
    const int n_off = is_b ? (n_base - 1024) : n_base;

    const int a_mi = tid & 127;
    const int a_k4 = tid >> 7;
    const int m = m_base + a_mi;
    const int s_idx = m >> 6, b_idx = m & 63;
    const long emb_row = (long)token[b_idx * SS + s_idx] * EE;

    const int b_n = tid & 63;
    const int b_k4 = tid >> 6;
    const float* wrow = W + (long)(n_off + b_n) * EE;

    const int tx = tid & 15;   // m interleaved
    const int ty = tid >> 4;   // 4 n each
    float acc[8][4];
#pragma unroll
    for (int i = 0; i < 8; i++)
#pragma unroll
        for (int j = 0; j < 4; j++) acc[i][j] = 0.f;

    for (int kt = 0; kt < EE; kt += 16) {
        float4 av0 = *(const float4*)(emb + emb_row + kt + a_k4 * 8);
        float4 av1 = *(const float4*)(emb + emb_row + kt + a_k4 * 8 + 4);
        float4 bv  = *(const float4*)(wrow + kt + b_k4 * 4);
        __syncthreads();
        {
            int k0 = a_k4 * 8;
            As[k0 + 0][a_mi] = av0.x; As[k0 + 1][a_mi] = av0.y;
            As[k0 + 2][a_mi] = av0.z; As[k0 + 3][a_mi] = av0.w;
            As[k0 + 4][a_mi] = av1.x; As[k0 + 5][a_mi] = av1.y;
            As[k0 + 6][a_mi] = av1.z; As[k0 + 7][a_mi] = av1.w;
            int k1 = b_k4 * 4;
            Bs[k1 + 0][b_n] = bv.x; Bs[k1 + 1][b_n] = bv.y;
            Bs[k1 + 2][b_n] = bv.z; Bs[k1 + 3][b_n] = bv.w;
        }
        __syncthreads();
#pragma unroll
        for (int k = 0; k < 16; k++) {
            float am[8];
#pragma unroll
            for (int i = 0; i < 8; i++) am[i] = As[k][tx + 16 * i];
            float4 b0 = *(const float4*)&Bs[k][ty * 4];
            float bn[4] = {b0.x, b0.y, b0.z, b0.w};
#pragma unroll
            for (int i = 0; i < 8; i++)
#pragma unroll
                for (int j = 0; j < 4; j++)
                    acc[i][j] = fmaf(am[i], bn[j], acc[i][j]);
        }
    }
    const float* bi_p = is_b ? b_ih_b : b_ih_f;
    const float* bh_p = is_b ? b_hh_b : b_hh_f;
    float bb[4];
#pragma unroll
    for (int j = 0; j < 4; j++) {
        int n = n_off + ty * 4 + j;
        bb[j] = bi_p[n] + bh_p[n];
    }
    float* Gout = is_b ? GbT : GfT;
#pragma unroll
    for (int i = 0; i < 8; i++) {
        int mm = m_base + tx + 16 * i;
        int ss = mm >> 6, bbx = mm & 63;
#pragma unroll
        for (int j = 0; j < 4; j++) {
            long addr = ((long)ss * G4 + n_off + ty * 4 + j) * BB + bbx;
            Gout[addr] = acc[i][j] + bb[j];
        }
    }
}

// ---------------------------------------------------------------- persistent BiLSTM
// 256 wgs: dir = bid>>7, bg = (bid>>5)&3 (16 b), cg = bid&31 (8 cols).
// matvec threads: kq = tid>>5 (8 K-slices of 32), col = (tid>>2)&7, b4 = tid&3 (4 b each)
// update threads: u<128: ub = u&15, ucol = u>>4
__global__ __launch_bounds__(256) void k_lstm(
    const float* __restrict__ GfT, const float* __restrict__ GbT,
    const float* __restrict__ whh_f, const float* __restrict__ whh_b,
    const float* __restrict__ c0,
    float* __restrict__ hbufT2,  // [par][dir][bg][k 256][b 16]
    float* __restrict__ hcatT,   // [s][n 512][b 64]
    int* __restrict__ cnt) {
    __shared__ float Wt[256 * PDP];       // [k][c*4+g], pitch 36 (36.9 KB)
    __shared__ float Ht[256 * HTP];       // [k][b16], pitch 20 (20.5 KB)
    __shared__ float Pd[8 * PDS];         // [kq][b16][n32 pad36] (18.4 KB)
    const int tid = threadIdx.x;
    const int bid = blockIdx.x;
    const int dir = bid >> 7;
    const int bg  = (bid >> 5) & 3;
    const int cg  = bid & 31;
    const int colbase = cg * 8;
    const float* whh = dir ? whh_b : whh_f;
    const float* GT  = dir ? GbT : GfT;

    const int kq  = tid >> 5;
    const int col = (tid >> 2) & 7;
    const int b4  = tid & 3;

    const int ub   = tid & 15;           // update mapping (tid<128)
    const int ucol = tid >> 4;
    const int ugb  = bg * 16 + ub;
    const int ugcol = colbase + ucol;

    // ---- preload W slice: Wt[k*36 + c*4 + g] = whh[(g*256 + colbase + c)*256 + k]
    {
        int r = tid >> 3;              // 0..31 = c*4+g
        int c_ = r >> 2, g_ = r & 3;
        const float* src = whh + (long)(g_ * HD + colbase + c_) * HD;
        int kc = tid & 7;
#pragma unroll
        for (int j = 0; j < 8; ++j) {
            int k = kc * 32 + j * 4;
            float4 v = *(const float4*)(src + k);
            Wt[(k + 0) * PDP + r] = v.x;
            Wt[(k + 1) * PDP + r] = v.y;
            Wt[(k + 2) * PDP + r] = v.z;
            Wt[(k + 3) * PDP + r] = v.w;
        }
    }
    float cst = 0.f;
    float4 gq = make_float4(0.f, 0.f, 0.f, 0.f);
    if (tid < 128) {
        cst = c0[dir * (BB * HD) + ugb * HD + ugcol];
        // prologue G prefetch for t=0
        int sidx0 = dir ? (SS - 1) : 0;
        const float* Gs = GT + (long)sidx0 * (G4 * BB);
        gq.x = Gs[(0 * HD + ugcol) * BB + ugb];
        gq.y = Gs[(1 * HD + ugcol) * BB + ugb];
        gq.z = Gs[(2 * HD + ugcol) * BB + ugb];
        gq.w = Gs[(3 * HD + ugcol) * BB + ugb];
    }

    int* myc = cnt + (dir * 4 + bg) * 256;   // counters 1 KB apart
    const int kk0 = tid >> 2, cc = tid & 3;  // staging mapping

    for (int t = 0; t < SS; ++t) {
        const int sidx = dir ? (SS - 1 - t) : t;
        const int par = t & 1;

        // ---- stage Ht[k][b] from hbufT2 slab (fully coalesced IC loads)
        {
            const float* slab = hbufT2 + (((long)par * 2 + dir) * 4 + bg) * 4096;
            const float* p = slab + tid * 4;
            float4 v0, v1, v2, v3;
            ld4x_sc(p, p + 1024, p + 2048, p + 3072, v0, v1, v2, v3);
            *(float4*)&Ht[(0 * 64 + kk0) * HTP + cc * 4] = v0;
            *(float4*)&Ht[(1 * 64 + kk0) * HTP + cc * 4] = v1;
            *(float4*)&Ht[(2 * 64 + kk0) * HTP + cc * 4] = v2;
            *(float4*)&Ht[(3 * 64 + kk0) * HTP + cc * 4] = v3;
        }
        __syncthreads();

        // ---- matvec: acc[i(b4)][j(gate)] over K slice [kq*32, kq*32+32)
        float4 a0 = {0,0,0,0}, a1 = {0,0,0,0}, a2 = {0,0,0,0}, a3 = {0,0,0,0};
        {
            const float* hp = Ht + kq * 32 * HTP + b4 * 4;
            const float* wp = Wt + kq * 32 * PDP + col * 4;
#pragma unroll 8
            for (int kk = 0; kk < 32; ++kk) {
                float4 h4 = *(const float4*)(hp + kk * HTP);
                float4 w4 = *(const float4*)(wp + kk * PDP);
                a0.x = fmaf(h4.x, w4.x, a0.x); a0.y = fmaf(h4.x, w4.y, a0.y);
                a0.z = fmaf(h4.x, w4.z, a0.z); a0.w = fmaf(h4.x, w4.w, a0.w);
                a1.x = fmaf(h4.y, w4.x, a1.x); a1.y = fmaf(h4.y, w4.y, a1.y);
                a1.z = fmaf(h4.y, w4.z, a1.z); a1.w = fmaf(h4.y, w4.w, a1.w);
                a2.x = fmaf(h4.z, w4.x, a2.x); a2.y = fmaf(h4.z, w4.y, a2.y);
                a2.z = fmaf(h4.z, w4.z, a2.z); a2.w = fmaf(h4.z, w4.w, a2.w);
                a3.x = fmaf(h4.w, w4.x, a3.x); a3.y = fmaf(h4.w, w4.y, a3.y);
                a3.z = fmaf(h4.w, w4.z, a3.z); a3.w = fmaf(h4.w, w4.w, a3.w);
            }
        }
        {
            float* pdst = Pd + kq * PDS + (b4 * 4) * PDP + col * 4;
            *(float4*)(pdst + 0 * PDP) = a0;
            *(float4*)(pdst + 1 * PDP) = a1;
            *(float4*)(pdst + 2 * PDP) = a2;
            *(float4*)(pdst + 3 * PDP) = a3;
        }
        __syncthreads();

        // ---- reduce + gates + state update (tid < 128)
        if (tid < 128) {
            float4 s = {0,0,0,0};
            const float* pr = Pd + ub * PDP + ucol * 4;
#pragma unroll
            for (int q = 0; q < 8; ++q) {
                float4 p = *(const float4*)(pr + q * PDS);
                s.x += p.x; s.y += p.y; s.z += p.z; s.w += p.w;
            }
            float gi = gq.x + s.x;
            float gf = gq.y + s.y;
            float gg = gq.z + s.z;
            float go = gq.w + s.w;
            float cn = sigm(gf) * cst + sigm(gi) * tanhf(gg);
            float hn = sigm(go) * tanhf(cn);
            cst = cn;
            hcatT[((long)sidx * 512 + dir * 256 + ugcol) * BB + ugb] = hn;
            if (t < SS - 1) {
                st_sc(hbufT2 + ((((long)(par ^ 1)) * 2 + dir) * 4 + bg) * 4096
                             + ugcol * 16 + ub, hn);
                // prefetch G for t+1 (hidden under the barrier spin)
                int sidx2 = dir ? (SS - 2 - t) : (t + 1);
                const float* Gs = GT + (long)sidx2 * (G4 * BB);
                gq.x = Gs[(0 * HD + ugcol) * BB + ugb];
                gq.y = Gs[(1 * HD + ugcol) * BB + ugb];
                gq.z = Gs[(2 * HD + ugcol) * BB + ugb];
                gq.w = Gs[(3 * HD + ugcol) * BB + ugb];
            }
        }

        if (t < SS - 1) {
            __syncthreads();   // all update threads' st_sc done (vmcnt in st_sc)
            if (tid == 0) {
                __hip_atomic_fetch_add(myc, 1, __ATOMIC_RELAXED, __HIP_MEMORY_SCOPE_AGENT);
                const int target = 32 * (t + 1);
                int budget = 1 << 20;   // deadlock escape only
                while (ld_sc_int(myc) < target && --budget) {}
            }
            __syncthreads();
        }
    }
}

// ---------------------------------------------------------------- tag projection (transposed)
// featsT[s][n 16][b 64]; grid 256 blocks (one s each), 256 threads
__global__ __launch_bounds__(256) void k_feats(const float* __restrict__ hcatT,
                                               const float* __restrict__ W_tag,
                                               const float* __restrict__ b_tag,
                                               float* __restrict__ featsT) {
    __shared__ float WT[512 * 16];   // [k][n] 32KB
    __shared__ float Hc[128 * 64];   // [kk][b] 32KB
    const int tid = threadIdx.x;
    const int s = blockIdx.x;
    // stage W^T (one-time)
    for (int j = 0; j < 32; ++j) {
        int idx = j * 256 + tid;
        int n = idx >> 9, k = idx & 511;
        WT[k * 16 + n] = W_tag[n * 512 + k];
    }
    const int b = tid & 63;
    const int ng = tid >> 6;        // 4 tags each
    float4 acc = {0, 0, 0, 0};
    for (int c = 0; c < 4; ++c) {
        const int k0 = c * 128;
        __syncthreads();
        // stage Hc[kk][b] = hcatT[s][k0+kk][b]
        {
            int kk = tid >> 4, bch = tid & 15;
#pragma unroll
            for (int j = 0; j < 8; ++j) {
                int kkk = j * 16 + kk;
                *(float4*)&Hc[kkk * 64 + bch * 4] =
                    *(const float4*)&hcatT[((long)s * 512 + k0 + kkk) * 64 + bch * 4];
            }
        }
        __syncthreads();
#pragma unroll 8
        for (int kk = 0; kk < 128; ++kk) {
            float h = Hc[kk * 64 + b];
            float4 w = *(const float4*)&WT[(k0 + kk) * 16 + ng * 4];
            acc.x = fmaf(h, w.x, acc.x);
            acc.y = fmaf(h, w.y, acc.y);
            acc.z = fmaf(h, w.z, acc.z);
            acc.w = fmaf(h, w.w, acc.w);
        }
    }
    featsT[((long)s * TT + ng * 4 + 0) * BB + b] = acc.x + b_tag[ng * 4 + 0];
    featsT[((long)s * TT + ng * 4 + 1) * BB + b] = acc.y + b_tag[ng * 4 + 1];
    featsT[((long)s * TT + ng * 4 + 2) * BB + b] = acc.z + b_tag[ng * 4 + 2];
    featsT[((long)s * TT + ng * 4 + 3) * BB + b] = acc.w + b_tag[ng * 4 + 3];
}

// ---------------------------------------------------------------- Viterbi + backtrack
__global__ __launch_bounds__(64) void k_viterbi(const float* __restrict__ featsT,
                                                const float* __restrict__ trans,
                                                int* __restrict__ out) {
    __shared__ float tr[16][17];
    __shared__ float fv[2][4][16];
    __shared__ unsigned char bp[4][256][16];
    const int lane = threadIdx.x;
    const int bi = lane >> 4, nx = lane & 15;
    const int b = blockIdx.x * 4 + bi;

    for (int i = lane; i < 256; i += 64) tr[i >> 4][i & 15] = trans[i];
    fv[0][bi][nx] = (nx == 14) ? 0.f : -10000.f;   // START = 14
    __syncthreads();

    int cur = 0;
    for (int s = 0; s < SS; s++) {
        float fe = featsT[((long)s * TT + nx) * BB + b];
        float best = -3.4e38f;
        int bestp = 0;
#pragma unroll
        for (int p = 0; p < 16; p++) {
            float sc = (fv[cur][bi][p] + tr[nx][p]) + fe;  // ref op order
            if (sc > best) { best = sc; bestp = p; }       // first-max wins
        }
        fv[cur ^ 1][bi][nx] = best;
        bp[bi][s][nx] = (unsigned char)bestp;
        __syncthreads();
        cur ^= 1;
    }
    float bv = fv[cur][bi][nx] + tr[15][nx];       // STOP = 15
    int bidx = nx;
#pragma unroll
    for (int off = 1; off < 16; off <<= 1) {
        float ov = __shfl_xor(bv, off, 64);
        int oi = __shfl_xor(bidx, off, 64);
        if (ov > bv || (ov == bv && oi < bidx)) { bv = ov; bidx = oi; }
    }
    if (nx == 0) {
        int tag = bidx;
        for (int s = SS - 1; s > 0; --s) {
            out[b * SS + s] = tag;
            tag = bp[bi][s][tag];
        }
        out[b * SS] = tag;
    }
}

// ---------------------------------------------------------------- launcher
extern "C" void kernel_launch(void* const* d_in, const int* in_sizes, int n_in,
                              void* d_out, int out_size, void* d_ws, size_t ws_size,
                              hipStream_t stream) {
    const int*   token  = (const int*)  d_in[0];
    const float* emb    = (const float*)d_in[1];
    const float* w_ih_f = (const float*)d_in[2];
    const float* w_hh_f = (const float*)d_in[3];
    const float* b_ih_f = (const float*)d_in[4];
    const float* b_hh_f = (const float*)d_in[5];
    const float* w_ih_b = (const float*)d_in[6];
    const float* w_hh_b = (const float*)d_in[7];
    const float* b_ih_b = (const float*)d_in[8];
    const float* b_hh_b = (const float*)d_in[9];
    const float* W_tag  = (const float*)d_in[10];
    const float* b_tag  = (const float*)d_in[11];
    const float* trans  = (const float*)d_in[12];
    const float* h0     = (const float*)d_in[13];
    const float* c0     = (const float*)d_in[14];
    int* out = (int*)d_out;

    char* ws = (char*)d_ws;
    float* GfT    = (float*)(ws);                                     // 64 MiB
    float* GbT    = (float*)(ws + ((size_t)64 << 20));                // 64 MiB
    float* hcatT  = (float*)(ws + ((size_t)128 << 20));               // 32 MiB
    float* featsT = (float*)(ws + ((size_t)160 << 20));               // 1 MiB
    float* hbufT2 = (float*)(ws + ((size_t)161 << 20));               // 256 KiB
    int*   cnt    = (int*)  (ws + ((size_t)161 << 20) + (512 << 10)); // 8 KiB

    k_init<<<dim3(129), dim3(256), 0, stream>>>(h0, hbufT2, cnt);
    k_gemm_in<<<dim3(128, 32), dim3(256), 0, stream>>>(
        token, emb, w_ih_f, w_ih_b, b_ih_f, b_hh_f, b_ih_b, b_hh_b, GfT, GbT);
    k_lstm<<<dim3(256), dim3(256), 0, stream>>>(
        GfT, GbT, w_hh_f, w_hh_b, c0, hbufT2, hcatT, cnt);
    k_feats<<<dim3(256), dim3(256), 0, stream>>>(hcatT, W_tag, b_tag, featsT);
    k_viterbi<<<dim3(16), dim3(64), 0, stream>>>(featsT, trans, out);
}

// Round 10
// 1266.024 us; speedup vs baseline: 2.6578x; 1.1525x over previous
//
#include <hip/hip_runtime.h>
#include <math.h>

#define SS 256      // sequence length S
#define BB 64       // batch B
#define EE 256      // embedding E
#define HD 256      // hidden per direction
#define G4 1024     // 4*HD
#define TT 16       // tags
#define HTP 20      // Ht pitch (floats)
#define PDP 36      // Pd row pitch
#define PDS 576     // Pd kq slab (16*36)
#define FLS 64      // flag line stride (ints) = 256B

__device__ __forceinline__ float sigm(float x) { return 1.0f / (1.0f + expf(-x)); }

// ---- device-coherent (Infinity-Cache) accessors: bypass L1/L2, no fences needed
__device__ __forceinline__ void ld4x_sc(const float* p0, const float* p1,
                                        const float* p2, const float* p3,
                                        float4& r0, float4& r1,
                                        float4& r2, float4& r3) {
    asm volatile(
        "global_load_dwordx4 %0, %4, off sc0 sc1\n\t"
        "global_load_dwordx4 %1, %5, off sc0 sc1\n\t"
        "global_load_dwordx4 %2, %6, off sc0 sc1\n\t"
        "global_load_dwordx4 %3, %7, off sc0 sc1\n\t"
        "s_waitcnt vmcnt(0)"
        : "=&v"(r0), "=&v"(r1), "=&v"(r2), "=&v"(r3)
        : "v"(p0), "v"(p1), "v"(p2), "v"(p3)
        : "memory");
}
__device__ __forceinline__ void st_sc(float* p, float v) {
    asm volatile(
        "global_store_dword %0, %1, off sc0 sc1\n\t"
        "s_waitcnt vmcnt(0)"
        :: "v"(p), "v"(v)
        : "memory");
}
__device__ __forceinline__ void st_sc_int(int* p, int v) {
    asm volatile(
        "global_store_dword %0, %1, off sc0 sc1\n\t"
        "s_waitcnt vmcnt(0)"
        :: "v"(p), "v"(v)
        : "memory");
}
__device__ __forceinline__ int ld_sc_int(const int* p) {
    int v;
    asm volatile(
        "global_load_dword %0, %1, off sc0 sc1\n\t"
        "s_waitcnt vmcnt(0)"
        : "=v"(v) : "v"(p) : "memory");
    return v;
}

// ---------------------------------------------------------------- init h (parity0) + zero flags
// hbufT2 layout: [par][dir][bg(4)][k(256)][b(16)]
__global__ __launch_bounds__(256) void k_init(const float* __restrict__ h0,
                                              float* __restrict__ hbufT2,
                                              int* __restrict__ flags) {
    int bid = blockIdx.x;
    if (bid < 128) {
        int i = bid * 256 + threadIdx.x;      // 32768 = 2*64*256 ; h0 = [dir][b][k]
        int dir = i >> 14, b = (i >> 8) & 63, k = i & 255;
        hbufT2[((dir * 4) + (b >> 4)) * 4096 + k * 16 + (b & 15)] = h0[i];
    } else {
        int i = (bid - 128) * 256 + threadIdx.x;   // 64 blocks -> 16384 ints
        flags[i] = 0;
    }
}

// ---------------------------------------------------------------- input projection
// G_T[s][n(1024)][b(64)] = emb[token(s,b)] . W_ih[n] + (b_ih[n]+b_hh[n])
__global__ __launch_bounds__(256) void k_gemm_in(
    const int* __restrict__ token, const float* __restrict__ emb,
    const float* __restrict__ w_ih_f, const float* __restrict__ w_ih_b,
    const float* __restrict__ b_ih_f, const float* __restrict__ b_hh_f,
    const float* __restrict__ b_ih_b, const float* __restrict__ b_hh_b,
    float* __restrict__ GfT, float* __restrict__ GbT) {
    __shared__ float As[16][128];
    __shared__ float Bs[16][64];
    const int tid = threadIdx.x;
    const int m_base = blockIdx.x * 128;
    const int n_base = blockIdx.y * 64;
    const bool is_b = (n_base >= 1024);
    const float* W = is_b ? w_ih_b : w_ih_f;
    const int n_off = is_b ? (n_base - 1024) : n_base;

    const int a_mi = tid & 127;
    const int a_k4 = tid >> 7;
    const int m = m_base + a_mi;
    const int s_idx = m >> 6, b_idx = m & 63;
    const long emb_row = (long)token[b_idx * SS + s_idx] * EE;

    const int b_n = tid & 63;
    const int b_k4 = tid >> 6;
    const float* wrow = W + (long)(n_off + b_n) * EE;

    const int tx = tid & 15;   // m interleaved
    const int ty = tid >> 4;   // 4 n each
    float acc[8][4];
#pragma unroll
    for (int i = 0; i < 8; i++)
#pragma unroll
        for (int j = 0; j < 4; j++) acc[i][j] = 0.f;

    for (int kt = 0; kt < EE; kt += 16) {
        float4 av0 = *(const float4*)(emb + emb_row + kt + a_k4 * 8);
        float4 av1 = *(const float4*)(emb + emb_row + kt + a_k4 * 8 + 4);
        float4 bv  = *(const float4*)(wrow + kt + b_k4 * 4);
        __syncthreads();
        {
            int k0 = a_k4 * 8;
            As[k0 + 0][a_mi] = av0.x; As[k0 + 1][a_mi] = av0.y;
            As[k0 + 2][a_mi] = av0.z; As[k0 + 3][a_mi] = av0.w;
            As[k0 + 4][a_mi] = av1.x; As[k0 + 5][a_mi] = av1.y;
            As[k0 + 6][a_mi] = av1.z; As[k0 + 7][a_mi] = av1.w;
            int k1 = b_k4 * 4;
            Bs[k1 + 0][b_n] = bv.x; Bs[k1 + 1][b_n] = bv.y;
            Bs[k1 + 2][b_n] = bv.z; Bs[k1 + 3][b_n] = bv.w;
        }
        __syncthreads();
#pragma unroll
        for (int k = 0; k < 16; k++) {
            float am[8];
#pragma unroll
            for (int i = 0; i < 8; i++) am[i] = As[k][tx + 16 * i];
            float4 b0 = *(const float4*)&Bs[k][ty * 4];
            float bn[4] = {b0.x, b0.y, b0.z, b0.w};
#pragma unroll
            for (int i = 0; i < 8; i++)
#pragma unroll
                for (int j = 0; j < 4; j++)
                    acc[i][j] = fmaf(am[i], bn[j], acc[i][j]);
        }
    }
    const float* bi_p = is_b ? b_ih_b : b_ih_f;
    const float* bh_p = is_b ? b_hh_b : b_hh_f;
    float bb[4];
#pragma unroll
    for (int j = 0; j < 4; j++) {
        int n = n_off + ty * 4 + j;
        bb[j] = bi_p[n] + bh_p[n];
    }
    float* Gout = is_b ? GbT : GfT;
#pragma unroll
    for (int i = 0; i < 8; i++) {
        int mm = m_base + tx + 16 * i;
        int ss = mm >> 6, bbx = mm & 63;
#pragma unroll
        for (int j = 0; j < 4; j++) {
            long addr = ((long)ss * G4 + n_off + ty * 4 + j) * BB + bbx;
            Gout[addr] = acc[i][j] + bb[j];
        }
    }
}

// ---------------------------------------------------------------- persistent BiLSTM
// 256 wgs: dir = bid>>7, bg = (bid>>5)&3 (16 b), cg = bid&31 (8 cols).
// matvec threads: kq = tid>>5, col = (tid>>2)&7, b4 = tid&3. W slice in VGPRs.
// Sync: per-wg flag line; producers store own line; consumers poll 32 lines in parallel.
__global__ __launch_bounds__(256, 1) void k_lstm(
    const float* __restrict__ GfT, const float* __restrict__ GbT,
    const float* __restrict__ whh_f, const float* __restrict__ whh_b,
    const float* __restrict__ c0,
    float* __restrict__ hbufT2,  // [par][dir][bg][k 256][b 16]
    float* __restrict__ hcatT,   // [s][n 512][b 64]
    int* __restrict__ flags) {   // [wg 256][64]
    __shared__ float Wt[256 * PDP];       // staging only (one-time)
    __shared__ float Ht[256 * HTP];       // [k][b16] pitch 20 (no skew — r9 skew was buggy)
    __shared__ float Pd[8 * PDS];         // [kq][b16][n32 pad36]
    const int tid = threadIdx.x;
    const int bid = blockIdx.x;
    const int dir = bid >> 7;
    const int bg  = (bid >> 5) & 3;
    const int cg  = bid & 31;
    const int colbase = cg * 8;
    const float* whh = dir ? whh_b : whh_f;
    const float* GT  = dir ? GbT : GfT;

    const int kq  = tid >> 5;
    const int col = (tid >> 2) & 7;
    const int b4  = tid & 3;

    const int ub   = tid & 15;           // update mapping (tid<128)
    const int ucol = tid >> 4;
    const int ugb  = bg * 16 + ub;
    const int ugcol = colbase + ucol;

    // ---- stage W slice into LDS (one-time): Wt[k*36 + c*4 + g] = whh[(g*256+colbase+c)*256 + k]
    {
        int r = tid >> 3;              // 0..31 = c*4+g
        int c_ = r >> 2, g_ = r & 3;
        const float* src = whh + (long)(g_ * HD + colbase + c_) * HD;
        int kc = tid & 7;
#pragma unroll
        for (int j = 0; j < 8; ++j) {
            int k = kc * 32 + j * 4;
            float4 v = *(const float4*)(src + k);
            Wt[(k + 0) * PDP + r] = v.x;
            Wt[(k + 1) * PDP + r] = v.y;
            Wt[(k + 2) * PDP + r] = v.z;
            Wt[(k + 3) * PDP + r] = v.w;
        }
    }
    __syncthreads();
    // ---- pull W slice into registers (32 float4, static index)
    float4 w[32];
    {
        const float* wb = Wt + (kq * 32) * PDP + col * 4;
#pragma unroll
        for (int kk = 0; kk < 32; ++kk) w[kk] = *(const float4*)(wb + kk * PDP);
    }

    float cst = 0.f;
    float4 gq = make_float4(0.f, 0.f, 0.f, 0.f);
    if (tid < 128) {
        cst = c0[dir * (BB * HD) + ugb * HD + ugcol];
        int sidx0 = dir ? (SS - 1) : 0;
        const float* Gs = GT + (long)sidx0 * (G4 * BB);
        gq.x = Gs[(0 * HD + ugcol) * BB + ugb];
        gq.y = Gs[(1 * HD + ugcol) * BB + ugb];
        gq.z = Gs[(2 * HD + ugcol) * BB + ugb];
        gq.w = Gs[(3 * HD + ugcol) * BB + ugb];
    }

    int* myflag = flags + bid * FLS;
    int* grpfl  = flags + ((dir * 4 + bg) * 32) * FLS;
    const int kk0 = tid >> 2, cc = tid & 3;           // staging mapping

    for (int t = 0; t < SS; ++t) {
        const int sidx = dir ? (SS - 1 - t) : t;
        const int par = t & 1;

        // ---- stage Ht[k][b] from hbufT2 slab (coalesced IC loads)
        {
            const float* slab = hbufT2 + (((long)par * 2 + dir) * 4 + bg) * 4096;
            const float* p = slab + tid * 4;
            float4 v0, v1, v2, v3;
            ld4x_sc(p, p + 1024, p + 2048, p + 3072, v0, v1, v2, v3);
            *(float4*)&Ht[(0 * 64 + kk0) * HTP + cc * 4] = v0;
            *(float4*)&Ht[(1 * 64 + kk0) * HTP + cc * 4] = v1;
            *(float4*)&Ht[(2 * 64 + kk0) * HTP + cc * 4] = v2;
            *(float4*)&Ht[(3 * 64 + kk0) * HTP + cc * 4] = v3;
        }
        __syncthreads();

        // ---- matvec: register W, 1 LDS read per k (8-lane broadcast across col)
        float4 a0 = {0,0,0,0}, a1 = {0,0,0,0}, a2 = {0,0,0,0}, a3 = {0,0,0,0};
        {
            const float* hp = Ht + (kq * 32) * HTP + b4 * 4;
#pragma unroll
            for (int kk = 0; kk < 32; ++kk) {
                float4 h4 = *(const float4*)(hp + kk * HTP);
                float4 w4 = w[kk];
                a0.x = fmaf(h4.x, w4.x, a0.x); a0.y = fmaf(h4.x, w4.y, a0.y);
                a0.z = fmaf(h4.x, w4.z, a0.z); a0.w = fmaf(h4.x, w4.w, a0.w);
                a1.x = fmaf(h4.y, w4.x, a1.x); a1.y = fmaf(h4.y, w4.y, a1.y);
                a1.z = fmaf(h4.y, w4.z, a1.z); a1.w = fmaf(h4.y, w4.w, a1.w);
                a2.x = fmaf(h4.z, w4.x, a2.x); a2.y = fmaf(h4.z, w4.y, a2.y);
                a2.z = fmaf(h4.z, w4.z, a2.z); a2.w = fmaf(h4.z, w4.w, a2.w);
                a3.x = fmaf(h4.w, w4.x, a3.x); a3.y = fmaf(h4.w, w4.y, a3.y);
                a3.z = fmaf(h4.w, w4.z, a3.z); a3.w = fmaf(h4.w, w4.w, a3.w);
            }
        }
        {
            float* pdst = Pd + kq * PDS + (b4 * 4) * PDP + col * 4;
            *(float4*)(pdst + 0 * PDP) = a0;
            *(float4*)(pdst + 1 * PDP) = a1;
            *(float4*)(pdst + 2 * PDP) = a2;
            *(float4*)(pdst + 3 * PDP) = a3;
        }
        __syncthreads();

        // ---- reduce + gates + state update (tid < 128)
        if (tid < 128) {
            float4 s = {0,0,0,0};
            const float* pr = Pd + ub * PDP + ucol * 4;
#pragma unroll
            for (int q = 0; q < 8; ++q) {
                float4 p = *(const float4*)(pr + q * PDS);
                s.x += p.x; s.y += p.y; s.z += p.z; s.w += p.w;
            }
            float gi = gq.x + s.x;
            float gf = gq.y + s.y;
            float gg = gq.z + s.z;
            float go = gq.w + s.w;
            float cn = sigm(gf) * cst + sigm(gi) * tanhf(gg);
            float hn = sigm(go) * tanhf(cn);
            cst = cn;
            hcatT[((long)sidx * 512 + dir * 256 + ugcol) * BB + ugb] = hn;
            if (t < SS - 1) {
                st_sc(hbufT2 + ((((long)(par ^ 1)) * 2 + dir) * 4 + bg) * 4096
                             + ugcol * 16 + ub, hn);
                // prefetch G for t+1 (hidden under the barrier wait)
                int sidx2 = dir ? (SS - 2 - t) : (t + 1);
                const float* Gs = GT + (long)sidx2 * (G4 * BB);
                gq.x = Gs[(0 * HD + ugcol) * BB + ugb];
                gq.y = Gs[(1 * HD + ugcol) * BB + ugb];
                gq.z = Gs[(2 * HD + ugcol) * BB + ugb];
                gq.w = Gs[(3 * HD + ugcol) * BB + ugb];
            }
        }

        if (t < SS - 1) {
            __syncthreads();   // all update threads' st_sc complete (vmcnt in st_sc)
            if (tid < 64) {
                if (tid == 0) st_sc_int(myflag, t + 1);   // own line: no serialization
                const int target = t + 1;
                int budget = 1 << 16;
                for (;;) {
                    int v = target;
                    if (tid < 32) v = ld_sc_int(grpfl + tid * FLS);
                    if (__all(v >= target) || --budget <= 0) break;
                }
            }
            __syncthreads();
        }
    }
}

// ---------------------------------------------------------------- tag projection (transposed)
// featsT[s][n 16][b 64]; grid 256 blocks (one s each), 256 threads
__global__ __launch_bounds__(256) void k_feats(const float* __restrict__ hcatT,
                                               const float* __restrict__ W_tag,
                                               const float* __restrict__ b_tag,
                                               float* __restrict__ featsT) {
    __shared__ float WT[512 * 16];   // [k][n] 32KB
    __shared__ float Hc[128 * 64];   // [kk][b] 32KB
    const int tid = threadIdx.x;
    const int s = blockIdx.x;
    for (int j = 0; j < 32; ++j) {
        int idx = j * 256 + tid;
        int n = idx >> 9, k = idx & 511;
        WT[k * 16 + n] = W_tag[n * 512 + k];
    }
    const int b = tid & 63;
    const int ng = tid >> 6;        // 4 tags each
    float4 acc = {0, 0, 0, 0};
    for (int c = 0; c < 4; ++c) {
        const int k0 = c * 128;
        __syncthreads();
        {
            int kk = tid >> 4, bch = tid & 15;
#pragma unroll
            for (int j = 0; j < 8; ++j) {
                int kkk = j * 16 + kk;
                *(float4*)&Hc[kkk * 64 + bch * 4] =
                    *(const float4*)&hcatT[((long)s * 512 + k0 + kkk) * 64 + bch * 4];
            }
        }
        __syncthreads();
#pragma unroll 8
        for (int kk = 0; kk < 128; ++kk) {
            float h = Hc[kk * 64 + b];
            float4 w = *(const float4*)&WT[(k0 + kk) * 16 + ng * 4];
            acc.x = fmaf(h, w.x, acc.x);
            acc.y = fmaf(h, w.y, acc.y);
            acc.z = fmaf(h, w.z, acc.z);
            acc.w = fmaf(h, w.w, acc.w);
        }
    }
    featsT[((long)s * TT + ng * 4 + 0) * BB + b] = acc.x + b_tag[ng * 4 + 0];
    featsT[((long)s * TT + ng * 4 + 1) * BB + b] = acc.y + b_tag[ng * 4 + 1];
    featsT[((long)s * TT + ng * 4 + 2) * BB + b] = acc.z + b_tag[ng * 4 + 2];
    featsT[((long)s * TT + ng * 4 + 3) * BB + b] = acc.w + b_tag[ng * 4 + 3];
}

// ---------------------------------------------------------------- Viterbi + backtrack
__global__ __launch_bounds__(64) void k_viterbi(const float* __restrict__ featsT,
                                                const float* __restrict__ trans,
                                                int* __restrict__ out) {
    __shared__ float tr[16][17];
    __shared__ float fv[2][4][16];
    __shared__ unsigned char bp[4][256][16];
    const int lane = threadIdx.x;
    const int bi = lane >> 4, nx = lane & 15;
    const int b = blockIdx.x * 4 + bi;

    for (int i = lane; i < 256; i += 64) tr[i >> 4][i & 15] = trans[i];
    fv[0][bi][nx] = (nx == 14) ? 0.f : -10000.f;   // START = 14
    __syncthreads();

    int cur = 0;
    for (int s = 0; s < SS; s++) {
        float fe = featsT[((long)s * TT + nx) * BB + b];
        float best = -3.4e38f;
        int bestp = 0;
#pragma unroll
        for (int p = 0; p < 16; p++) {
            float sc = (fv[cur][bi][p] + tr[nx][p]) + fe;  // ref op order
            if (sc > best) { best = sc; bestp = p; }       // first-max wins
        }
        fv[cur ^ 1][bi][nx] = best;
        bp[bi][s][nx] = (unsigned char)bestp;
        __syncthreads();
        cur ^= 1;
    }
    float bv = fv[cur][bi][nx] + tr[15][nx];       // STOP = 15
    int bidx = nx;
#pragma unroll
    for (int off = 1; off < 16; off <<= 1) {
        float ov = __shfl_xor(bv, off, 64);
        int oi = __shfl_xor(bidx, off, 64);
        if (ov > bv || (ov == bv && oi < bidx)) { bv = ov; bidx = oi; }
    }
    if (nx == 0) {
        int tag = bidx;
        for (int s = SS - 1; s > 0; --s) {
            out[b * SS + s] = tag;
            tag = bp[bi][s][tag];
        }
        out[b * SS] = tag;
    }
}

// ---------------------------------------------------------------- launcher
extern "C" void kernel_launch(void* const* d_in, const int* in_sizes, int n_in,
                              void* d_out, int out_size, void* d_ws, size_t ws_size,
                              hipStream_t stream) {
    const int*   token  = (const int*)  d_in[0];
    const float* emb    = (const float*)d_in[1];
    const float* w_ih_f = (const float*)d_in[2];
    const float* w_hh_f = (const float*)d_in[3];
    const float* b_ih_f = (const float*)d_in[4];
    const float* b_hh_f = (const float*)d_in[5];
    const float* w_ih_b = (const float*)d_in[6];
    const float* w_hh_b = (const float*)d_in[7];
    const float* b_ih_b = (const float*)d_in[8];
    const float* b_hh_b = (const float*)d_in[9];
    const float* W_tag  = (const float*)d_in[10];
    const float* b_tag  = (const float*)d_in[11];
    const float* trans  = (const float*)d_in[12];
    const float* h0     = (const float*)d_in[13];
    const float* c0     = (const float*)d_in[14];
    int* out = (int*)d_out;

    char* ws = (char*)d_ws;
    float* GfT    = (float*)(ws);                                     // 64 MiB
    float* GbT    = (float*)(ws + ((size_t)64 << 20));                // 64 MiB
    float* hcatT  = (float*)(ws + ((size_t)128 << 20));               // 32 MiB
    float* featsT = (float*)(ws + ((size_t)160 << 20));               // 1 MiB
    float* hbufT2 = (float*)(ws + ((size_t)161 << 20));               // 256 KiB
    int*   flags  = (int*)  (ws + ((size_t)161 << 20) + (512 << 10)); // 64 KiB

    k_init<<<dim3(192), dim3(256), 0, stream>>>(h0, hbufT2, flags);
    k_gemm_in<<<dim3(128, 32), dim3(256), 0, stream>>>(
        token, emb, w_ih_f, w_ih_b, b_ih_f, b_hh_f, b_ih_b, b_hh_b, GfT, GbT);
    k_lstm<<<dim3(256), dim3(256), 0, stream>>>(
        GfT, GbT, w_hh_f, w_hh_b, c0, hbufT2, hcatT, flags);
    k_feats<<<dim3(256), dim3(256), 0, stream>>>(hcatT, W_tag, b_tag, featsT);
    k_viterbi<<<dim3(16), dim3(64), 0, stream>>>(featsT, trans, out);
}